// Round 19
// baseline (296.664 us; speedup 1.0000x reference)
//
#include <hip/hip_runtime.h>
#include <math.h>

#define N_B 4
#define IMG 192
#define P 194   // padded pitch for bf16 activation buffers (1-pixel zero halo)

typedef __attribute__((ext_vector_type(8))) short short8;
typedef __attribute__((ext_vector_type(4))) float f32x4;

__device__ __forceinline__ unsigned f2bf(float f) {
  unsigned u = __float_as_uint(f);
  return (u + 0x7fffu + ((u >> 16) & 1u)) >> 16;   // RNE to bf16 bits
}
__device__ __forceinline__ float bf2f(unsigned b) {
  return __uint_as_float(b << 16);
}
// LDS swizzle for 128B pixel rows
__device__ __forceinline__ int swz(int pix) {
  return (pix & 7) << 4;
}
// async global->LDS 16B copy (lane's data lands at lds_base + lane*16)
__device__ __forceinline__ void gload_lds16(const void* g, void* l) {
  __builtin_amdgcn_global_load_lds(
      (const __attribute__((address_space(1))) void*)g,
      (__attribute__((address_space(3))) void*)l, 16, 0, 0);
}

// ---------------- down path ----------------
__global__ void k_d1(const float* __restrict__ x, const float* __restrict__ w,
                     float* __restrict__ out) {
  int idx = blockIdx.x * 256 + threadIdx.x;            // (4,16,48,48)
  if (idx >= N_B * 16 * 48 * 48) return;
  int xq = idx % 48; int t = idx / 48; int yq = t % 48; t /= 48;
  int oc = t % 16; int b = t / 16;
  const float* xp = x + (b * IMG + yq * 4) * IMG + xq * 4;
  const float* wp = w + oc * 16;
  float s = 0.f;
#pragma unroll
  for (int dy = 0; dy < 4; ++dy)
#pragma unroll
    for (int dx = 0; dx < 4; ++dx)
      s = fmaf(xp[dy * IMG + dx], wp[dy * 4 + dx], s);
  out[idx] = fmaxf(s, 0.f);
}

// d2 writes PIXEL-MAJOR: h2t[(b*144 + yq*12 + xq)*256 + oc]
// weights pre-transposed: d2t[(ci*16+tap)*256 + oc] (lane-coalesced)
__global__ void k_d2(const float* __restrict__ h1, const float* __restrict__ d2t,
                     float* __restrict__ out) {
  int idx = blockIdx.x * 256 + threadIdx.x;            // (4,144,256): oc fast
  if (idx >= N_B * 144 * 256) return;
  int oc = idx & 255; int t = idx >> 8; int p = t % 144; int b = t / 144;
  int yq = p / 12, xq = p % 12;
  float s = 0.f;
  for (int ci = 0; ci < 16; ++ci) {
    const float* ip = h1 + ((b * 16 + ci) * 48 + yq * 4) * 48 + xq * 4;
    const float* wp = d2t + (ci * 16) * 256 + oc;
#pragma unroll
    for (int dy = 0; dy < 4; ++dy)
#pragma unroll
      for (int dx = 0; dx < 4; ++dx)
        s = fmaf(ip[dy * 48 + dx], wp[(dy * 4 + dx) * 256], s);
  }
  out[((size_t)b * 144 + p) * 256 + oc] = fmaxf(s, 0.f);
}

// d3: 4 pixels per thread, oc fast; grid 144 blocks x 256 thr.
__global__ __launch_bounds__(256) void k_d3(const float* __restrict__ h2t,
                                            const float* __restrict__ w3p,
                                            float* __restrict__ out) {
  int tid = threadIdx.x;
  int blk = blockIdx.x;                    // 4b x 9pg x 4og = 144
  int og = blk & 3; int t = blk >> 2; int pg = t % 9; int b = t / 9;
  int oc = og * 256 + tid;
  const float* w0 = w3p + oc;
  const float* base[4];
#pragma unroll
  for (int k = 0; k < 4; ++k) {
    int p6 = pg * 4 + k;
    int yq = p6 / 6, xq = p6 % 6;
    base[k] = h2t + ((size_t)b * 144 + (2 * yq) * 12 + 2 * xq) * 256;
  }
  float a0[4] = {0, 0, 0, 0}, a1[4] = {0, 0, 0, 0};
  float a2[4] = {0, 0, 0, 0}, a3[4] = {0, 0, 0, 0};
  for (int ci = 0; ci < 256; ++ci) {
    float w0v = w0[(size_t)(0 * 256 + ci) * 1024];
    float w1v = w0[(size_t)(1 * 256 + ci) * 1024];
    float w2v = w0[(size_t)(2 * 256 + ci) * 1024];
    float w3v = w0[(size_t)(3 * 256 + ci) * 1024];
#pragma unroll
    for (int k = 0; k < 4; ++k) {
      a0[k] = fmaf(base[k][ci], w0v, a0[k]);
      a1[k] = fmaf(base[k][256 + ci], w1v, a1[k]);
      a2[k] = fmaf(base[k][12 * 256 + ci], w2v, a2[k]);
      a3[k] = fmaf(base[k][12 * 256 + 256 + ci], w3v, a3[k]);
    }
  }
#pragma unroll
  for (int k = 0; k < 4; ++k) {
    int p6 = pg * 4 + k;
    out[((size_t)b * 36 + p6) * 1024 + oc] =
        fmaxf((a0[k] + a1[k]) + (a2[k] + a3[k]), 0.f);
  }
}

// fused: d4 (1x1) + STE quantize + 3x qcm + up-conv + depth_to_space
// ALL weights pre-transposed: d4t[ic][160], qt[l][ic][160], upt[ic][1024]
__global__ __launch_bounds__(512) void k_mid(
    const float* __restrict__ h3t, const float* __restrict__ d4t,
    const float* __restrict__ qt, const float* __restrict__ q1_b,
    const float* __restrict__ q2_b, const float* __restrict__ q3_b,
    const float* __restrict__ upt, const float* __restrict__ up_b,
    float* __restrict__ x4_out, float* __restrict__ xcomp_out,
    float* __restrict__ y_out) {
  __shared__ float hv[1024];
  __shared__ float part[512];
  __shared__ float tv[160];
  __shared__ float xrv[160];
  int blk = blockIdx.x;
  int b = blk / 36, p = blk % 36;
  int tid = threadIdx.x;
  for (int i = tid; i < 1024; i += 512) hv[i] = h3t[(size_t)blk * 1024 + i];
  __syncthreads();
  {
    int half = tid >> 8, oc = tid & 255;
    float s = 0.f;
    if (oc < 154) {
      const float* wp = d4t + (size_t)half * 512 * 160 + oc;
      const float* hp = hv + half * 512;
      float a0 = 0.f, a1 = 0.f, a2 = 0.f, a3 = 0.f;
      for (int i = 0; i < 512; i += 4) {
        a0 = fmaf(hp[i], wp[(size_t)i * 160], a0);
        a1 = fmaf(hp[i + 1], wp[(size_t)(i + 1) * 160], a1);
        a2 = fmaf(hp[i + 2], wp[(size_t)(i + 2) * 160], a2);
        a3 = fmaf(hp[i + 3], wp[(size_t)(i + 3) * 160], a3);
      }
      s = (a0 + a1) + (a2 + a3);
    }
    part[tid] = s;
  }
  __syncthreads();
  if (tid < 154) {
    float s = part[tid] + part[tid + 256];
    x4_out[(b * 154 + tid) * 36 + p] = s;
    float q = floorf(s / 0.01f) * 0.01f;
    xrv[tid] = q;
    tv[tid] = q;
  }
  __syncthreads();
  const float* qb[3] = {q1_b, q2_b, q3_b};
  for (int l = 0; l < 3; ++l) {
    float s = 0.f;
    if (tid < 154) {
      const float* wp = qt + (size_t)l * 154 * 160 + tid;
      float a0 = 0.f, a1 = 0.f;
      int i = 0;
      for (; i + 1 < 154; i += 2) {
        a0 = fmaf(tv[i], wp[(size_t)i * 160], a0);
        a1 = fmaf(tv[i + 1], wp[(size_t)(i + 1) * 160], a1);
      }
      if (i < 154) a0 = fmaf(tv[i], wp[(size_t)i * 160], a0);
      s = qb[l][tid] + a0 + a1;
    }
    __syncthreads();
    if (tid < 154) tv[tid] = fmaxf(s, 0.f) + tv[tid];
    __syncthreads();
  }
  if (tid < 154) {
    float xc = tv[tid] + xrv[tid];
    tv[tid] = xc;
    xcomp_out[(b * 154 + tid) * 36 + p] = xc;
  }
  __syncthreads();
  int h = p / 6, w6 = p % 6;
#pragma unroll
  for (int k = 0; k < 2; ++k) {
    int co = k * 512 + tid;
    const float* wp = upt + co;
    float a0 = 0.f, a1 = 0.f;
    int i = 0;
    for (; i + 1 < 154; i += 2) {
      a0 = fmaf(tv[i], wp[(size_t)i * 1024], a0);
      a1 = fmaf(tv[i + 1], wp[(size_t)(i + 1) * 1024], a1);
    }
    if (i < 154) a0 = fmaf(tv[i], wp[(size_t)i * 1024], a0);
    float s = up_b[co] + a0 + a1;
    int i32 = co >> 5, j = co & 31;
    y_out[(b * IMG + h * 32 + i32) * IMG + w6 * 32 + j] = s;
  }
}

// c1: 3x3 conv 1->64 + prelu; writes B1, S1=b1+y (bf16, PADDED NHWC)
__global__ __launch_bounds__(256) void k_c1b(const float* __restrict__ y,
                                             const float* __restrict__ w,
                                             const float* __restrict__ bias,
                                             const float* __restrict__ a_p,
                                             short* __restrict__ B1,
                                             short* __restrict__ S1) {
  int idx = blockIdx.x * 256 + threadIdx.x;            // pixels
  if (idx >= N_B * IMG * IMG) return;
  int X = idx % IMG; int t = idx / IMG; int Y = t % IMG; int b = t / IMG;
  float p[9];
#pragma unroll
  for (int dy = 0; dy < 3; ++dy)
#pragma unroll
    for (int dx = 0; dx < 3; ++dx) {
      int gy = Y + dy - 1, gx = X + dx - 1;
      p[dy * 3 + dx] = ((unsigned)gy < (unsigned)IMG && (unsigned)gx < (unsigned)IMG)
                           ? y[(b * IMG + gy) * IMG + gx]
                           : 0.f;
    }
  float a = *a_p;
  float yc = p[4];
  size_t base = (((size_t)b * P + Y + 1) * P + X + 1) * 64;
  for (int oc = 0; oc < 64; oc += 8) {
    unsigned bw[4], sw[4];
#pragma unroll
    for (int j = 0; j < 8; ++j) {
      float s = bias[oc + j];
      const float* wq = w + (oc + j) * 9;
#pragma unroll
      for (int k = 0; k < 9; ++k) s = fmaf(p[k], wq[k], s);
      s = s >= 0.f ? s : a * s;
      float sv = s + yc;
      if (j & 1) { bw[j >> 1] |= f2bf(s) << 16; sw[j >> 1] |= f2bf(sv) << 16; }
      else       { bw[j >> 1] = f2bf(s);        sw[j >> 1] = f2bf(sv); }
    }
    *(uint4*)(B1 + base + oc) = make_uint4(bw[0], bw[1], bw[2], bw[3]);
    *(uint4*)(S1 + base + oc) = make_uint4(sw[0], sw[1], sw[2], sw[3]);
  }
}

// ---- merged prep: conv packs + d3 pack + halo rings + mid/d2 transposes ----
#define WPA (64 * 64 * 9)          // 36864
#define WPB (256 * 64 * 9)         // 147456
#define WD3N (4 * 256 * 1024)      // 1048576
#define RINGN (4 * 4 * 772 * 8)    // 98816
#define D4TN (1024 * 154)          // 157696
#define QTN (3 * 154 * 154)        // 71148
#define UPTN (154 * 1024)          // 157696
#define D2TN (256 * 16 * 16)       // 65536
#define PREPN (3 * WPA + WPB + WD3N + RINGN + D4TN + QTN + UPTN + D2TN)
__global__ __launch_bounds__(256) void k_prep(
    const float* __restrict__ w2, const float* __restrict__ w3,
    const float* __restrict__ w4, const float* __restrict__ w5,
    const float* __restrict__ d3w, const float* __restrict__ d4w,
    const float* __restrict__ q1w, const float* __restrict__ q2w,
    const float* __restrict__ q3w, const float* __restrict__ upw,
    const float* __restrict__ d2w,
    short* __restrict__ o2, short* __restrict__ o3,
    short* __restrict__ o4, short* __restrict__ o5,
    float* __restrict__ w3p, float* __restrict__ d4t,
    float* __restrict__ qt, float* __restrict__ upt,
    float* __restrict__ d2t,
    short* __restrict__ s0, short* __restrict__ s1,
    short* __restrict__ s2, short* __restrict__ s3) {
  int idx = blockIdx.x * 256 + threadIdx.x;
  if (idx < 3 * WPA + WPB) {
    int which, id;
    if (idx < WPA) { which = 0; id = idx; }
    else if (idx < 2 * WPA) { which = 1; id = idx - WPA; }
    else if (idx < 3 * WPA) { which = 2; id = idx - 2 * WPA; }
    else { which = 3; id = idx - 3 * WPA; }
    const float* w = (which == 0) ? w2 : (which == 1) ? w3 : (which == 2) ? w4 : w5;
    short* o = (which == 0) ? o2 : (which == 1) ? o3 : (which == 2) ? o4 : o5;
    int OC = (which == 3) ? 256 : 64;
    int ic = id & 63; int t = id >> 6; int r = t % OC; int tap = t / OC;
    int oc = (which < 3) ? (((r >> 2) & 3) * 16 + ((r >> 4) & 3) * 4 + (r & 3)) : r;
    int ks = ic >> 5, lg = (ic >> 3) & 3, j = ic & 7, li = r & 15, ocblk = r >> 4;
    size_t dst = ((size_t)(tap * 2 + ks) * (OC >> 4) + ocblk) * 512 +
                 (lg * 16 + li) * 8 + j;
    o[dst] = (short)f2bf(w[((size_t)oc * 64 + ic) * 9 + tap]);
    return;
  }
  idx -= 3 * WPA + WPB;
  if (idx < WD3N) {
    // source-linear read (coalesced), scattered write
    int tap = idx & 3; int ci = (idx >> 2) & 255; int oc = idx >> 10;
    w3p[((size_t)tap * 256 + ci) * 1024 + oc] = d3w[idx];
    return;
  }
  idx -= WD3N;
  if (idx < RINGN) {
    int chunk = idx & 7; int t = idx >> 3;
    int r = t % 772; t /= 772; int b = t % 4; int buf = t / 4;
    int y, x;
    if (r < 194) { y = 0; x = r; }
    else if (r < 388) { y = 193; x = r - 194; }
    else { int q = r - 388; y = 1 + (q >> 1); x = (q & 1) ? 193 : 0; }
    short* p = (buf == 0) ? s0 : (buf == 1) ? s1 : (buf == 2) ? s2 : s3;
    *(uint4*)(p + (((size_t)b * P + y) * P + x) * 64 + chunk * 8) =
        make_uint4(0u, 0u, 0u, 0u);
    return;
  }
  idx -= RINGN;
  if (idx < D4TN) {                 // d4t[ic*160 + oc] = d4w[oc*1024 + ic]
    int oc = idx % 154; int ic = idx / 154;
    d4t[(size_t)ic * 160 + oc] = d4w[(size_t)oc * 1024 + ic];
    return;
  }
  idx -= D4TN;
  if (idx < QTN) {                  // qt[l][ic*160 + oc]
    int l = idx / (154 * 154); int rem = idx % (154 * 154);
    int oc = rem % 154; int ic = rem / 154;
    const float* qw = (l == 0) ? q1w : (l == 1) ? q2w : q3w;
    qt[(size_t)l * 154 * 160 + (size_t)ic * 160 + oc] =
        qw[(size_t)oc * 154 + ic];
    return;
  }
  idx -= QTN;
  if (idx < UPTN) {                 // upt[ic*1024 + co] = upw[co*154 + ic]
    int co = idx % 1024; int ic = idx / 1024;
    upt[(size_t)ic * 1024 + co] = upw[(size_t)co * 154 + ic];
    return;
  }
  idx -= UPTN;
  if (idx < D2TN) {                 // d2t[(ci*16+tap)*256 + oc]
    int oc = idx & 255; int t = idx >> 8; int tap = t & 15; int ci = t >> 4;
    d2t[((size_t)ci * 16 + tap) * 256 + oc] =
        d2w[((size_t)oc * 16 + ci) * 16 + tap];
  }
}

// ---- c2-c4: MFMA implicit-GEMM 3x3 conv, 4x48 tile, 64 oc, 4 waves ----
template <int MODE>
__global__ __launch_bounds__(256) void k_conv3x3n(
    const short* __restrict__ sin, const short* __restrict__ bprev,
    const short* __restrict__ wbf, const float* __restrict__ bias,
    const float* __restrict__ a_p, short* __restrict__ bout,
    short* __restrict__ sout) {
  __shared__ __align__(16) char smem[300 * 128];
  int tid = threadIdx.x;
  int b = blockIdx.z;
  int x0 = blockIdx.x * 48, y0 = blockIdx.y * 4;
  int w = tid >> 6, lane = tid & 63, li = lane & 15, lg = lane >> 4;

  for (int c = w; c < 38; c += 4) {
    int o = c * 1024 + lane * 16;
    if (o < 300 * 128) {
      int pix = o >> 7;
      int icq = ((o >> 4) & 7) ^ (pix & 7);
      const short* src = sin +
          (((size_t)b * P + y0 + pix / 50) * P + x0 + pix % 50) * 64 + icq * 8;
      gload_lds16(src, smem + c * 1024);
    }
  }
  __syncthreads();

  const short* abase = wbf + (lane << 3);
  const int astride = 64 * 32;

  f32x4 acc[4][3];
#pragma unroll
  for (int mt = 0; mt < 4; ++mt)
#pragma unroll
    for (int nt = 0; nt < 3; ++nt) acc[mt][nt] = (f32x4){0.f, 0.f, 0.f, 0.f};

#define LOADA(s, dst)                                                          \
  {                                                                            \
    const short* p_ = abase + (size_t)(s) * astride;                           \
    _Pragma("unroll") for (int mt = 0; mt < 4; ++mt)                           \
        dst[mt] = *(const short8*)(p_ + mt * 512);                             \
  }
#define LOADB(s, dst)                                                          \
  {                                                                            \
    const int tap_ = (s) >> 1, ks_ = (s) & 1;                                  \
    const int dy_ = tap_ / 3, dx_ = tap_ % 3;                                  \
    _Pragma("unroll") for (int nt = 0; nt < 3; ++nt) {                         \
      int pix_ = (w + dy_) * 50 + nt * 16 + dx_ + li;                          \
      int byte_ = (pix_ * 128 + ks_ * 64 + lg * 16) ^ swz(pix_);               \
      dst[nt] = *(const short8*)(smem + byte_);                                \
    }                                                                          \
  }

  short8 Abuf[2][4];
  short8 Bbuf[3];
  LOADA(0, Abuf[0]);
#pragma unroll
  for (int s = 0; s < 18; ++s) {
    if (s + 1 < 18) LOADA(s + 1, Abuf[(s + 1) & 1]);
    LOADB(s, Bbuf);
    short8* Ac = Abuf[s & 1];
#pragma unroll
    for (int mt = 0; mt < 4; ++mt)
#pragma unroll
      for (int nt = 0; nt < 3; ++nt)
        acc[mt][nt] = __builtin_amdgcn_mfma_f32_16x16x32_bf16(Ac[mt], Bbuf[nt],
                                                              acc[mt][nt], 0, 0, 0);
  }
#undef LOADA
#undef LOADB

  float a = *a_p;
  int gy = y0 + w;
#pragma unroll
  for (int nt = 0; nt < 3; ++nt) {
    int gx = x0 + nt * 16 + li;
    float r[16];
#pragma unroll
    for (int mt = 0; mt < 4; ++mt) {
      float4 bv = *(const float4*)(bias + lg * 16 + mt * 4);
      f32x4 v = acc[mt][nt];
      float t0 = v[0] + bv.x, t1 = v[1] + bv.y, t2 = v[2] + bv.z, t3 = v[3] + bv.w;
      r[mt * 4 + 0] = t0 >= 0.f ? t0 : a * t0;
      r[mt * 4 + 1] = t1 >= 0.f ? t1 : a * t1;
      r[mt * 4 + 2] = t2 >= 0.f ? t2 : a * t2;
      r[mt * 4 + 3] = t3 >= 0.f ? t3 : a * t3;
    }
    size_t pi = (((size_t)b * P + gy + 1) * P + gx + 1) * 64 + lg * 16;
    if (MODE == 0) {
      uint4 u0 = make_uint4(f2bf(r[0]) | (f2bf(r[1]) << 16),
                            f2bf(r[2]) | (f2bf(r[3]) << 16),
                            f2bf(r[4]) | (f2bf(r[5]) << 16),
                            f2bf(r[6]) | (f2bf(r[7]) << 16));
      uint4 u1 = make_uint4(f2bf(r[8]) | (f2bf(r[9]) << 16),
                            f2bf(r[10]) | (f2bf(r[11]) << 16),
                            f2bf(r[12]) | (f2bf(r[13]) << 16),
                            f2bf(r[14]) | (f2bf(r[15]) << 16));
      *(uint4*)(bout + pi) = u0;
      *(uint4*)(bout + pi + 8) = u1;
    }
    uint4 p0 = *(const uint4*)(bprev + pi);
    uint4 p1 = *(const uint4*)(bprev + pi + 8);
    unsigned pw[8] = {p0.x, p0.y, p0.z, p0.w, p1.x, p1.y, p1.z, p1.w};
    unsigned so[8];
#pragma unroll
    for (int k = 0; k < 8; ++k) {
      float s0 = r[2 * k] + bf2f(pw[k] & 0xffffu);
      float s1 = r[2 * k + 1] + bf2f(pw[k] >> 16);
      so[k] = f2bf(s0) | (f2bf(s1) << 16);
    }
    *(uint4*)(sout + pi) = make_uint4(so[0], so[1], so[2], so[3]);
    *(uint4*)(sout + pi + 8) = make_uint4(so[4], so[5], so[6], so[7]);
  }
}

// ---- c5: 4x48 tile, 1 oc-group per block (r17 winner), fp32 NCHW out ----
__global__ __launch_bounds__(256) void k_conv5n(
    const short* __restrict__ sin, const short* __restrict__ wbf,
    const float* __restrict__ bias, float* __restrict__ fout) {
  __shared__ __align__(16) char smem[300 * 128];
  int tid = threadIdx.x;
  int g = blockIdx.z & 3, b = blockIdx.z >> 2;
  int x0 = blockIdx.x * 48, y0 = blockIdx.y * 4;
  int w = tid >> 6, lane = tid & 63, li = lane & 15, lg = lane >> 4;

  for (int c = w; c < 38; c += 4) {
    int o = c * 1024 + lane * 16;
    if (o < 300 * 128) {
      int pix = o >> 7;
      int icq = ((o >> 4) & 7) ^ (pix & 7);
      const short* src = sin +
          (((size_t)b * P + y0 + pix / 50) * P + x0 + pix % 50) * 64 + icq * 8;
      gload_lds16(src, smem + c * 1024);
    }
  }
  __syncthreads();

  const short* abase = wbf + (size_t)(g << 2) * 512 + (lane << 3);
  const int astride = 256 * 32;

  f32x4 acc[4][3];
#pragma unroll
  for (int mt = 0; mt < 4; ++mt)
#pragma unroll
    for (int nt = 0; nt < 3; ++nt) acc[mt][nt] = (f32x4){0.f, 0.f, 0.f, 0.f};

#define LOADA5(s, dst)                                                         \
  {                                                                            \
    const short* p_ = abase + (size_t)(s) * astride;                           \
    _Pragma("unroll") for (int mt = 0; mt < 4; ++mt)                           \
        dst[mt] = *(const short8*)(p_ + mt * 512);                             \
  }
#define LOADB5(s, dst)                                                         \
  {                                                                            \
    const int tap_ = (s) >> 1, ks_ = (s) & 1;                                  \
    const int dy_ = tap_ / 3, dx_ = tap_ % 3;                                  \
    _Pragma("unroll") for (int nt = 0; nt < 3; ++nt) {                         \
      int pix_ = (w + dy_) * 50 + nt * 16 + dx_ + li;                          \
      int byte_ = (pix_ * 128 + ks_ * 64 + lg * 16) ^ swz(pix_);               \
      dst[nt] = *(const short8*)(smem + byte_);                                \
    }                                                                          \
  }

  short8 Abuf[2][4];
  short8 Bbuf[3];
  LOADA5(0, Abuf[0]);
#pragma unroll
  for (int s = 0; s < 18; ++s) {
    if (s + 1 < 18) LOADA5(s + 1, Abuf[(s + 1) & 1]);
    LOADB5(s, Bbuf);
    short8* Ac = Abuf[s & 1];
#pragma unroll
    for (int mt = 0; mt < 4; ++mt)
#pragma unroll
      for (int nt = 0; nt < 3; ++nt)
        acc[mt][nt] = __builtin_amdgcn_mfma_f32_16x16x32_bf16(Bbuf[nt], Ac[mt],
                                                              acc[mt][nt], 0, 0, 0);
  }
#undef LOADA5
#undef LOADB5

  // swapped acc: lane reg j = pixel gx = x0+nt*16+lg*4+j, oc = g*64+mt*16+li
  int gy = y0 + w;
#pragma unroll
  for (int nt = 0; nt < 3; ++nt) {
    int gx = x0 + nt * 16 + lg * 4;
#pragma unroll
    for (int mt = 0; mt < 4; ++mt) {
      int oc = g * 64 + mt * 16 + li;
      float bv = bias[oc];
      f32x4 v = acc[mt][nt];
      *(float4*)(fout + (((size_t)b * 256 + oc) * IMG + gy) * IMG + gx) =
          make_float4(v[0] + bv, v[1] + bv, v[2] + bv, v[3] + bv);
    }
  }
}

// ---------------------------------------------------------------------------
extern "C" void kernel_launch(void* const* d_in, const int* in_sizes, int n_in,
                              void* d_out, int out_size, void* d_ws, size_t ws_size,
                              hipStream_t stream) {
  const float* x    = (const float*)d_in[0];
  const float* d1_w = (const float*)d_in[2];
  const float* d2_w = (const float*)d_in[3];
  const float* d3_w = (const float*)d_in[4];
  const float* d4_w = (const float*)d_in[5];
  const float* q1_w = (const float*)d_in[6];
  const float* q1_b = (const float*)d_in[7];
  const float* q2_w = (const float*)d_in[8];
  const float* q2_b = (const float*)d_in[9];
  const float* q3_w = (const float*)d_in[10];
  const float* q3_b = (const float*)d_in[11];
  const float* up_w = (const float*)d_in[12];
  const float* up_b = (const float*)d_in[13];
  const float* c1_w = (const float*)d_in[14];
  const float* c1_b = (const float*)d_in[15];
  const float* c1_a = (const float*)d_in[16];
  const float* c2_w = (const float*)d_in[17];
  const float* c2_b = (const float*)d_in[18];
  const float* c2_a = (const float*)d_in[19];
  const float* c3_w = (const float*)d_in[20];
  const float* c3_b = (const float*)d_in[21];
  const float* c3_a = (const float*)d_in[22];
  const float* c4_w = (const float*)d_in[23];
  const float* c4_b = (const float*)d_in[24];
  const float* c4_a = (const float*)d_in[25];
  const float* c5_w = (const float*)d_in[26];
  const float* c5_b = (const float*)d_in[27];

  float* out = (float*)d_out;
  float* ws  = (float*)d_ws;

  const size_t B5  = (size_t)N_B * 256 * IMG * IMG;
  const size_t SML = (size_t)N_B * 154 * 36;
  float* out_b5    = out;
  float* out_xcomp = out + B5;
  float* out_x4    = out + B5 + SML;

  const size_t PADBUF = (size_t)N_B * P * P * 64 / 2;   // floats per padded bf16 buf
  size_t off = 0;
  float* h1   = ws + off; off += (size_t)N_B * 16 * 48 * 48;
  float* h2t  = ws + off; off += (size_t)N_B * 144 * 256;
  float* h3t  = ws + off; off += (size_t)N_B * 36 * 1024;
  float* w3p  = ws + off; off += (size_t)4 * 256 * 1024;
  float* d4t  = ws + off; off += (size_t)1024 * 160;
  float* qt   = ws + off; off += (size_t)3 * 154 * 160;
  float* upt  = ws + off; off += (size_t)154 * 1024;
  float* d2t  = ws + off; off += (size_t)256 * 16 * 16;
  float* ybuf = ws + off; off += (size_t)N_B * IMG * IMG;
  short* sl0  = (short*)(ws + off); off += PADBUF;
  short* sl1  = (short*)(ws + off); off += PADBUF;
  short* sl2  = (short*)(ws + off); off += PADBUF;
  short* sl3  = (short*)(ws + off); off += PADBUF;
  short* wb2  = (short*)(ws + off); off += 9 * 64 * 64 / 2;
  short* wb3  = (short*)(ws + off); off += 9 * 64 * 64 / 2;
  short* wb4  = (short*)(ws + off); off += 9 * 64 * 64 / 2;
  short* wb5  = (short*)(ws + off); off += 9 * 256 * 64 / 2;

  // merged prep (one launch): conv packs + d3 pack + rings + transposes
  k_prep<<<(PREPN + 255) / 256, 256, 0, stream>>>(
      c2_w, c3_w, c4_w, c5_w, d3_w, d4_w, q1_w, q2_w, q3_w, up_w, d2_w,
      wb2, wb3, wb4, wb5, w3p, d4t, qt, upt, d2t, sl0, sl1, sl2, sl3);

  // ---- down path ----
  k_d1<<<(N_B * 16 * 48 * 48 + 255) / 256, 256, 0, stream>>>(x, d1_w, h1);
  k_d2<<<(N_B * 144 * 256 + 255) / 256, 256, 0, stream>>>(h1, d2t, h2t);
  k_d3<<<144, 256, 0, stream>>>(h2t, w3p, h3t);

  // ---- fused d4 + quantize + qcm x3 + up + depth_to_space ----
  k_mid<<<N_B * 36, 512, 0, stream>>>(h3t, d4t, qt, q1_b, q2_b, q3_b,
                                      upt, up_b, out_x4, out_xcomp, ybuf);

  // ---- refinement CNN ----
  k_c1b<<<(N_B * IMG * IMG + 255) / 256, 256, 0, stream>>>(ybuf, c1_w, c1_b, c1_a,
                                                           sl1 /*B1*/, sl0 /*S1*/);

  dim3 cg(4, 48, N_B);   // 4x48 tile: 768 blocks = 3/CU exact
  // c2: in S1(sl0), bprev B1(sl1) -> B2(sl2), S2(sl3)
  k_conv3x3n<0><<<cg, 256, 0, stream>>>(sl0, sl1, wb2, c2_b, c2_a, sl2, sl3);
  // c3: in S2(sl3), bprev B2(sl2) -> B3(sl1), S3(sl0)
  k_conv3x3n<0><<<cg, 256, 0, stream>>>(sl3, sl2, wb3, c3_b, c3_a, sl1, sl0);
  // c4: in S3(sl0), bprev B3(sl1) -> S4(sl3)
  k_conv3x3n<1><<<cg, 256, 0, stream>>>(sl0, sl1, wb4, c4_b, c4_a, nullptr, sl3);
  // c5: in S4(sl3) -> d_out fp32 NCHW; 4x48 tile, 1 oc-group (r17 winner)
  dim3 cg5(4, 48, N_B * 4);
  k_conv5n<<<cg5, 256, 0, stream>>>(sl3, wb5, c5_b, out_b5);
}

// Round 20
// 285.117 us; speedup vs baseline: 1.0405x; 1.0405x over previous
//
#include <hip/hip_runtime.h>
#include <math.h>

#define N_B 4
#define IMG 192
#define P 194   // padded pitch for bf16 activation buffers (1-pixel zero halo)

typedef __attribute__((ext_vector_type(8))) short short8;
typedef __attribute__((ext_vector_type(4))) float f32x4;

__device__ __forceinline__ unsigned f2bf(float f) {
  unsigned u = __float_as_uint(f);
  return (u + 0x7fffu + ((u >> 16) & 1u)) >> 16;   // RNE to bf16 bits
}
__device__ __forceinline__ float bf2f(unsigned b) {
  return __uint_as_float(b << 16);
}
// LDS swizzle for 128B pixel rows
__device__ __forceinline__ int swz(int pix) {
  return (pix & 7) << 4;
}
// async global->LDS 16B copy (lane's data lands at lds_base + lane*16)
__device__ __forceinline__ void gload_lds16(const void* g, void* l) {
  __builtin_amdgcn_global_load_lds(
      (const __attribute__((address_space(1))) void*)g,
      (__attribute__((address_space(3))) void*)l, 16, 0, 0);
}

// ---------------- down path ----------------
__global__ void k_d1(const float* __restrict__ x, const float* __restrict__ w,
                     float* __restrict__ out) {
  int idx = blockIdx.x * 256 + threadIdx.x;            // (4,16,48,48)
  if (idx >= N_B * 16 * 48 * 48) return;
  int xq = idx % 48; int t = idx / 48; int yq = t % 48; t /= 48;
  int oc = t % 16; int b = t / 16;
  const float* xp = x + (b * IMG + yq * 4) * IMG + xq * 4;
  const float* wp = w + oc * 16;
  float s = 0.f;
#pragma unroll
  for (int dy = 0; dy < 4; ++dy)
#pragma unroll
    for (int dx = 0; dx < 4; ++dx)
      s = fmaf(xp[dy * IMG + dx], wp[dy * 4 + dx], s);
  out[idx] = fmaxf(s, 0.f);
}

// d2 writes PIXEL-MAJOR: h2t[(b*144 + yq*12 + xq)*256 + oc]
// weights pre-transposed: d2t[(ci*16+tap)*256 + oc] (lane-coalesced)
__global__ void k_d2(const float* __restrict__ h1, const float* __restrict__ d2t,
                     float* __restrict__ out) {
  int idx = blockIdx.x * 256 + threadIdx.x;            // (4,144,256): oc fast
  if (idx >= N_B * 144 * 256) return;
  int oc = idx & 255; int t = idx >> 8; int p = t % 144; int b = t / 144;
  int yq = p / 12, xq = p % 12;
  float s = 0.f;
  for (int ci = 0; ci < 16; ++ci) {
    const float* ip = h1 + ((b * 16 + ci) * 48 + yq * 4) * 48 + xq * 4;
    const float* wp = d2t + (ci * 16) * 256 + oc;
#pragma unroll
    for (int dy = 0; dy < 4; ++dy)
#pragma unroll
      for (int dx = 0; dx < 4; ++dx)
        s = fmaf(ip[dy * 48 + dx], wp[(dy * 4 + dx) * 256], s);
  }
  out[((size_t)b * 144 + p) * 256 + oc] = fmaxf(s, 0.f);
}

// d3: oc is the FAST dim; writes TRANSPOSED h3t[(b*36 + p)*1024 + oc]
__global__ __launch_bounds__(256) void k_d3(const float* __restrict__ h2t,
                                            const float* __restrict__ w3p,
                                            float* __restrict__ out) {
  int idx = blockIdx.x * 256 + threadIdx.x;            // (4,36,1024)
  if (idx >= N_B * 36 * 1024) return;
  int oc = idx & 1023; int t = idx >> 10; int p6 = t % 36; int b = t / 36;
  int yq = p6 / 6, xq = p6 % 6;
  const float* p00 = h2t + ((size_t)b * 144 + (2 * yq) * 12 + 2 * xq) * 256;
  const float* p01 = p00 + 256;
  const float* p10 = p00 + 12 * 256;
  const float* p11 = p10 + 256;
  const float* w0 = w3p + oc;
  float a0 = 0.f, a1 = 0.f, a2 = 0.f, a3 = 0.f;
  for (int ci = 0; ci < 256; ++ci) {
    a0 = fmaf(p00[ci], w0[(size_t)(0 * 256 + ci) * 1024], a0);
    a1 = fmaf(p01[ci], w0[(size_t)(1 * 256 + ci) * 1024], a1);
    a2 = fmaf(p10[ci], w0[(size_t)(2 * 256 + ci) * 1024], a2);
    a3 = fmaf(p11[ci], w0[(size_t)(3 * 256 + ci) * 1024], a3);
  }
  out[((size_t)b * 36 + p6) * 1024 + oc] = fmaxf((a0 + a1) + (a2 + a3), 0.f);
}

// fused: d4 (1x1) + STE quantize + 3x qcm + up-conv + depth_to_space
// ALL weights pre-transposed: d4t[ic][160], qt[l][ic][160], upt[ic][1024]
__global__ __launch_bounds__(512) void k_mid(
    const float* __restrict__ h3t, const float* __restrict__ d4t,
    const float* __restrict__ qt, const float* __restrict__ q1_b,
    const float* __restrict__ q2_b, const float* __restrict__ q3_b,
    const float* __restrict__ upt, const float* __restrict__ up_b,
    float* __restrict__ x4_out, float* __restrict__ xcomp_out,
    float* __restrict__ y_out) {
  __shared__ float hv[1024];
  __shared__ float part[512];
  __shared__ float tv[160];
  __shared__ float xrv[160];
  int blk = blockIdx.x;
  int b = blk / 36, p = blk % 36;
  int tid = threadIdx.x;
  for (int i = tid; i < 1024; i += 512) hv[i] = h3t[(size_t)blk * 1024 + i];
  __syncthreads();
  {
    int half = tid >> 8, oc = tid & 255;
    float s = 0.f;
    if (oc < 154) {
      const float* wp = d4t + (size_t)half * 512 * 160 + oc;
      const float* hp = hv + half * 512;
      float a0 = 0.f, a1 = 0.f, a2 = 0.f, a3 = 0.f;
      for (int i = 0; i < 512; i += 4) {
        a0 = fmaf(hp[i], wp[(size_t)i * 160], a0);
        a1 = fmaf(hp[i + 1], wp[(size_t)(i + 1) * 160], a1);
        a2 = fmaf(hp[i + 2], wp[(size_t)(i + 2) * 160], a2);
        a3 = fmaf(hp[i + 3], wp[(size_t)(i + 3) * 160], a3);
      }
      s = (a0 + a1) + (a2 + a3);
    }
    part[tid] = s;
  }
  __syncthreads();
  if (tid < 154) {
    float s = part[tid] + part[tid + 256];
    x4_out[(b * 154 + tid) * 36 + p] = s;
    float q = floorf(s / 0.01f) * 0.01f;
    xrv[tid] = q;
    tv[tid] = q;
  }
  __syncthreads();
  const float* qb[3] = {q1_b, q2_b, q3_b};
  for (int l = 0; l < 3; ++l) {
    float s = 0.f;
    if (tid < 154) {
      const float* wp = qt + (size_t)l * 154 * 160 + tid;
      float a0 = 0.f, a1 = 0.f;
      int i = 0;
      for (; i + 1 < 154; i += 2) {
        a0 = fmaf(tv[i], wp[(size_t)i * 160], a0);
        a1 = fmaf(tv[i + 1], wp[(size_t)(i + 1) * 160], a1);
      }
      if (i < 154) a0 = fmaf(tv[i], wp[(size_t)i * 160], a0);
      s = qb[l][tid] + a0 + a1;
    }
    __syncthreads();
    if (tid < 154) tv[tid] = fmaxf(s, 0.f) + tv[tid];
    __syncthreads();
  }
  if (tid < 154) {
    float xc = tv[tid] + xrv[tid];
    tv[tid] = xc;
    xcomp_out[(b * 154 + tid) * 36 + p] = xc;
  }
  __syncthreads();
  int h = p / 6, w6 = p % 6;
#pragma unroll
  for (int k = 0; k < 2; ++k) {
    int co = k * 512 + tid;
    const float* wp = upt + co;
    float a0 = 0.f, a1 = 0.f;
    int i = 0;
    for (; i + 1 < 154; i += 2) {
      a0 = fmaf(tv[i], wp[(size_t)i * 1024], a0);
      a1 = fmaf(tv[i + 1], wp[(size_t)(i + 1) * 1024], a1);
    }
    if (i < 154) a0 = fmaf(tv[i], wp[(size_t)i * 1024], a0);
    float s = up_b[co] + a0 + a1;
    int i32 = co >> 5, j = co & 31;
    y_out[(b * IMG + h * 32 + i32) * IMG + w6 * 32 + j] = s;
  }
}

// c1: 3x3 conv 1->64 + prelu; writes B1, S1=b1+y (bf16, PADDED NHWC)
__global__ __launch_bounds__(256) void k_c1b(const float* __restrict__ y,
                                             const float* __restrict__ w,
                                             const float* __restrict__ bias,
                                             const float* __restrict__ a_p,
                                             short* __restrict__ B1,
                                             short* __restrict__ S1) {
  int idx = blockIdx.x * 256 + threadIdx.x;            // pixels
  if (idx >= N_B * IMG * IMG) return;
  int X = idx % IMG; int t = idx / IMG; int Y = t % IMG; int b = t / IMG;
  float p[9];
#pragma unroll
  for (int dy = 0; dy < 3; ++dy)
#pragma unroll
    for (int dx = 0; dx < 3; ++dx) {
      int gy = Y + dy - 1, gx = X + dx - 1;
      p[dy * 3 + dx] = ((unsigned)gy < (unsigned)IMG && (unsigned)gx < (unsigned)IMG)
                           ? y[(b * IMG + gy) * IMG + gx]
                           : 0.f;
    }
  float a = *a_p;
  float yc = p[4];
  size_t base = (((size_t)b * P + Y + 1) * P + X + 1) * 64;
  for (int oc = 0; oc < 64; oc += 8) {
    unsigned bw[4], sw[4];
#pragma unroll
    for (int j = 0; j < 8; ++j) {
      float s = bias[oc + j];
      const float* wq = w + (oc + j) * 9;
#pragma unroll
      for (int k = 0; k < 9; ++k) s = fmaf(p[k], wq[k], s);
      s = s >= 0.f ? s : a * s;
      float sv = s + yc;
      if (j & 1) { bw[j >> 1] |= f2bf(s) << 16; sw[j >> 1] |= f2bf(sv) << 16; }
      else       { bw[j >> 1] = f2bf(s);        sw[j >> 1] = f2bf(sv); }
    }
    *(uint4*)(B1 + base + oc) = make_uint4(bw[0], bw[1], bw[2], bw[3]);
    *(uint4*)(S1 + base + oc) = make_uint4(sw[0], sw[1], sw[2], sw[3]);
  }
}

// ---- merged prep: conv packs + d3 pack + halo rings + mid/d2 transposes ----
#define WPA (64 * 64 * 9)          // 36864
#define WPB (256 * 64 * 9)         // 147456
#define WD3N (4 * 256 * 1024)      // 1048576
#define RINGN (4 * 4 * 772 * 8)    // 98816
#define D4TN (1024 * 154)          // 157696
#define QTN (3 * 154 * 154)        // 71148
#define UPTN (154 * 1024)          // 157696
#define D2TN (256 * 16 * 16)       // 65536
#define PREPN (3 * WPA + WPB + WD3N + RINGN + D4TN + QTN + UPTN + D2TN)
__global__ __launch_bounds__(256) void k_prep(
    const float* __restrict__ w2, const float* __restrict__ w3,
    const float* __restrict__ w4, const float* __restrict__ w5,
    const float* __restrict__ d3w, const float* __restrict__ d4w,
    const float* __restrict__ q1w, const float* __restrict__ q2w,
    const float* __restrict__ q3w, const float* __restrict__ upw,
    const float* __restrict__ d2w,
    short* __restrict__ o2, short* __restrict__ o3,
    short* __restrict__ o4, short* __restrict__ o5,
    float* __restrict__ w3p, float* __restrict__ d4t,
    float* __restrict__ qt, float* __restrict__ upt,
    float* __restrict__ d2t,
    short* __restrict__ s0, short* __restrict__ s1,
    short* __restrict__ s2, short* __restrict__ s3) {
  int idx = blockIdx.x * 256 + threadIdx.x;
  if (idx < 3 * WPA + WPB) {
    int which, id;
    if (idx < WPA) { which = 0; id = idx; }
    else if (idx < 2 * WPA) { which = 1; id = idx - WPA; }
    else if (idx < 3 * WPA) { which = 2; id = idx - 2 * WPA; }
    else { which = 3; id = idx - 3 * WPA; }
    const float* w = (which == 0) ? w2 : (which == 1) ? w3 : (which == 2) ? w4 : w5;
    short* o = (which == 0) ? o2 : (which == 1) ? o3 : (which == 2) ? o4 : o5;
    int OC = (which == 3) ? 256 : 64;
    int ic = id & 63; int t = id >> 6; int r = t % OC; int tap = t / OC;
    int oc = (which < 3) ? (((r >> 2) & 3) * 16 + ((r >> 4) & 3) * 4 + (r & 3)) : r;
    int ks = ic >> 5, lg = (ic >> 3) & 3, j = ic & 7, li = r & 15, ocblk = r >> 4;
    size_t dst = ((size_t)(tap * 2 + ks) * (OC >> 4) + ocblk) * 512 +
                 (lg * 16 + li) * 8 + j;
    o[dst] = (short)f2bf(w[((size_t)oc * 64 + ic) * 9 + tap]);
    return;
  }
  idx -= 3 * WPA + WPB;
  if (idx < WD3N) {
    int oc = idx & 1023; int ci = (idx >> 10) & 255; int tap = idx >> 18;
    w3p[idx] = d3w[((size_t)oc * 256 + ci) * 4 + tap];
    return;
  }
  idx -= WD3N;
  if (idx < RINGN) {
    int chunk = idx & 7; int t = idx >> 3;
    int r = t % 772; t /= 772; int b = t % 4; int buf = t / 4;
    int y, x;
    if (r < 194) { y = 0; x = r; }
    else if (r < 388) { y = 193; x = r - 194; }
    else { int q = r - 388; y = 1 + (q >> 1); x = (q & 1) ? 193 : 0; }
    short* p = (buf == 0) ? s0 : (buf == 1) ? s1 : (buf == 2) ? s2 : s3;
    *(uint4*)(p + (((size_t)b * P + y) * P + x) * 64 + chunk * 8) =
        make_uint4(0u, 0u, 0u, 0u);
    return;
  }
  idx -= RINGN;
  if (idx < D4TN) {                 // d4t[ic*160 + oc] = d4w[oc*1024 + ic]
    int oc = idx % 154; int ic = idx / 154;
    d4t[(size_t)ic * 160 + oc] = d4w[(size_t)oc * 1024 + ic];
    return;
  }
  idx -= D4TN;
  if (idx < QTN) {                  // qt[l][ic*160 + oc]
    int l = idx / (154 * 154); int rem = idx % (154 * 154);
    int oc = rem % 154; int ic = rem / 154;
    const float* qw = (l == 0) ? q1w : (l == 1) ? q2w : q3w;
    qt[(size_t)l * 154 * 160 + (size_t)ic * 160 + oc] =
        qw[(size_t)oc * 154 + ic];
    return;
  }
  idx -= QTN;
  if (idx < UPTN) {                 // upt[ic*1024 + co] = upw[co*154 + ic]
    int co = idx % 1024; int ic = idx / 1024;
    upt[(size_t)ic * 1024 + co] = upw[(size_t)co * 154 + ic];
    return;
  }
  idx -= UPTN;
  if (idx < D2TN) {                 // d2t[(ci*16+tap)*256 + oc]
    int oc = idx & 255; int t = idx >> 8; int tap = t & 15; int ci = t >> 4;
    d2t[((size_t)ci * 16 + tap) * 256 + oc] =
        d2w[((size_t)oc * 16 + ci) * 16 + tap];
  }
}

// ---- c2-c4: MFMA implicit-GEMM 3x3 conv, 4x48 tile, 64 oc, 4 waves ----
template <int MODE>
__global__ __launch_bounds__(256) void k_conv3x3n(
    const short* __restrict__ sin, const short* __restrict__ bprev,
    const short* __restrict__ wbf, const float* __restrict__ bias,
    const float* __restrict__ a_p, short* __restrict__ bout,
    short* __restrict__ sout) {
  __shared__ __align__(16) char smem[300 * 128];
  int tid = threadIdx.x;
  int b = blockIdx.z;
  int x0 = blockIdx.x * 48, y0 = blockIdx.y * 4;
  int w = tid >> 6, lane = tid & 63, li = lane & 15, lg = lane >> 4;

  for (int c = w; c < 38; c += 4) {
    int o = c * 1024 + lane * 16;
    if (o < 300 * 128) {
      int pix = o >> 7;
      int icq = ((o >> 4) & 7) ^ (pix & 7);
      const short* src = sin +
          (((size_t)b * P + y0 + pix / 50) * P + x0 + pix % 50) * 64 + icq * 8;
      gload_lds16(src, smem + c * 1024);
    }
  }
  __syncthreads();

  const short* abase = wbf + (lane << 3);
  const int astride = 64 * 32;

  f32x4 acc[4][3];
#pragma unroll
  for (int mt = 0; mt < 4; ++mt)
#pragma unroll
    for (int nt = 0; nt < 3; ++nt) acc[mt][nt] = (f32x4){0.f, 0.f, 0.f, 0.f};

#define LOADA(s, dst)                                                          \
  {                                                                            \
    const short* p_ = abase + (size_t)(s) * astride;                           \
    _Pragma("unroll") for (int mt = 0; mt < 4; ++mt)                           \
        dst[mt] = *(const short8*)(p_ + mt * 512);                             \
  }
#define LOADB(s, dst)                                                          \
  {                                                                            \
    const int tap_ = (s) >> 1, ks_ = (s) & 1;                                  \
    const int dy_ = tap_ / 3, dx_ = tap_ % 3;                                  \
    _Pragma("unroll") for (int nt = 0; nt < 3; ++nt) {                         \
      int pix_ = (w + dy_) * 50 + nt * 16 + dx_ + li;                          \
      int byte_ = (pix_ * 128 + ks_ * 64 + lg * 16) ^ swz(pix_);               \
      dst[nt] = *(const short8*)(smem + byte_);                                \
    }                                                                          \
  }

  short8 Abuf[2][4];
  short8 Bbuf[3];
  LOADA(0, Abuf[0]);
#pragma unroll
  for (int s = 0; s < 18; ++s) {
    if (s + 1 < 18) LOADA(s + 1, Abuf[(s + 1) & 1]);
    LOADB(s, Bbuf);
    short8* Ac = Abuf[s & 1];
#pragma unroll
    for (int mt = 0; mt < 4; ++mt)
#pragma unroll
      for (int nt = 0; nt < 3; ++nt)
        acc[mt][nt] = __builtin_amdgcn_mfma_f32_16x16x32_bf16(Ac[mt], Bbuf[nt],
                                                              acc[mt][nt], 0, 0, 0);
  }
#undef LOADA
#undef LOADB

  float a = *a_p;
  int gy = y0 + w;
#pragma unroll
  for (int nt = 0; nt < 3; ++nt) {
    int gx = x0 + nt * 16 + li;
    float r[16];
#pragma unroll
    for (int mt = 0; mt < 4; ++mt) {
      float4 bv = *(const float4*)(bias + lg * 16 + mt * 4);
      f32x4 v = acc[mt][nt];
      float t0 = v[0] + bv.x, t1 = v[1] + bv.y, t2 = v[2] + bv.z, t3 = v[3] + bv.w;
      r[mt * 4 + 0] = t0 >= 0.f ? t0 : a * t0;
      r[mt * 4 + 1] = t1 >= 0.f ? t1 : a * t1;
      r[mt * 4 + 2] = t2 >= 0.f ? t2 : a * t2;
      r[mt * 4 + 3] = t3 >= 0.f ? t3 : a * t3;
    }
    size_t pi = (((size_t)b * P + gy + 1) * P + gx + 1) * 64 + lg * 16;
    if (MODE == 0) {
      uint4 u0 = make_uint4(f2bf(r[0]) | (f2bf(r[1]) << 16),
                            f2bf(r[2]) | (f2bf(r[3]) << 16),
                            f2bf(r[4]) | (f2bf(r[5]) << 16),
                            f2bf(r[6]) | (f2bf(r[7]) << 16));
      uint4 u1 = make_uint4(f2bf(r[8]) | (f2bf(r[9]) << 16),
                            f2bf(r[10]) | (f2bf(r[11]) << 16),
                            f2bf(r[12]) | (f2bf(r[13]) << 16),
                            f2bf(r[14]) | (f2bf(r[15]) << 16));
      *(uint4*)(bout + pi) = u0;
      *(uint4*)(bout + pi + 8) = u1;
    }
    uint4 p0 = *(const uint4*)(bprev + pi);
    uint4 p1 = *(const uint4*)(bprev + pi + 8);
    unsigned pw[8] = {p0.x, p0.y, p0.z, p0.w, p1.x, p1.y, p1.z, p1.w};
    unsigned so[8];
#pragma unroll
    for (int k = 0; k < 8; ++k) {
      float s0 = r[2 * k] + bf2f(pw[k] & 0xffffu);
      float s1 = r[2 * k + 1] + bf2f(pw[k] >> 16);
      so[k] = f2bf(s0) | (f2bf(s1) << 16);
    }
    *(uint4*)(sout + pi) = make_uint4(so[0], so[1], so[2], so[3]);
    *(uint4*)(sout + pi + 8) = make_uint4(so[4], so[5], so[6], so[7]);
  }
}

// ---- c5: 4x48 tile, operand-swapped, fp32 NCHW out; grid (4,48,16) ----
__global__ __launch_bounds__(256) void k_conv5n(
    const short* __restrict__ sin, const short* __restrict__ wbf,
    const float* __restrict__ bias, float* __restrict__ fout) {
  __shared__ __align__(16) char smem[300 * 128];
  int tid = threadIdx.x;
  int g = blockIdx.z & 3, b = blockIdx.z >> 2;
  int x0 = blockIdx.x * 48, y0 = blockIdx.y * 4;
  int w = tid >> 6, lane = tid & 63, li = lane & 15, lg = lane >> 4;

  for (int c = w; c < 38; c += 4) {
    int o = c * 1024 + lane * 16;
    if (o < 300 * 128) {
      int pix = o >> 7;
      int icq = ((o >> 4) & 7) ^ (pix & 7);
      const short* src = sin +
          (((size_t)b * P + y0 + pix / 50) * P + x0 + pix % 50) * 64 + icq * 8;
      gload_lds16(src, smem + c * 1024);
    }
  }
  __syncthreads();

  const short* abase = wbf + (size_t)(g << 2) * 512 + (lane << 3);
  const int astride = 256 * 32;

  f32x4 acc[4][3];
#pragma unroll
  for (int mt = 0; mt < 4; ++mt)
#pragma unroll
    for (int nt = 0; nt < 3; ++nt) acc[mt][nt] = (f32x4){0.f, 0.f, 0.f, 0.f};

#define LOADA5(s, dst)                                                         \
  {                                                                            \
    const short* p_ = abase + (size_t)(s) * astride;                           \
    _Pragma("unroll") for (int mt = 0; mt < 4; ++mt)                           \
        dst[mt] = *(const short8*)(p_ + mt * 512);                             \
  }
#define LOADB5(s, dst)                                                         \
  {                                                                            \
    const int tap_ = (s) >> 1, ks_ = (s) & 1;                                  \
    const int dy_ = tap_ / 3, dx_ = tap_ % 3;                                  \
    _Pragma("unroll") for (int nt = 0; nt < 3; ++nt) {                         \
      int pix_ = (w + dy_) * 50 + nt * 16 + dx_ + li;                          \
      int byte_ = (pix_ * 128 + ks_ * 64 + lg * 16) ^ swz(pix_);               \
      dst[nt] = *(const short8*)(smem + byte_);                                \
    }                                                                          \
  }

  short8 Abuf[2][4];
  short8 Bbuf[3];
  LOADA5(0, Abuf[0]);
#pragma unroll
  for (int s = 0; s < 18; ++s) {
    if (s + 1 < 18) LOADA5(s + 1, Abuf[(s + 1) & 1]);
    LOADB5(s, Bbuf);
    short8* Ac = Abuf[s & 1];
#pragma unroll
    for (int mt = 0; mt < 4; ++mt)
#pragma unroll
      for (int nt = 0; nt < 3; ++nt)
        acc[mt][nt] = __builtin_amdgcn_mfma_f32_16x16x32_bf16(Bbuf[nt], Ac[mt],
                                                              acc[mt][nt], 0, 0, 0);
  }
#undef LOADA5
#undef LOADB5

  // swapped acc: lane reg j = pixel gx = x0+nt*16+lg*4+j, oc = g*64+mt*16+li
  int gy = y0 + w;
#pragma unroll
  for (int nt = 0; nt < 3; ++nt) {
    int gx = x0 + nt * 16 + lg * 4;
#pragma unroll
    for (int mt = 0; mt < 4; ++mt) {
      int oc = g * 64 + mt * 16 + li;
      float bv = bias[oc];
      f32x4 v = acc[mt][nt];
      *(float4*)(fout + (((size_t)b * 256 + oc) * IMG + gy) * IMG + gx) =
          make_float4(v[0] + bv, v[1] + bv, v[2] + bv, v[3] + bv);
    }
  }
}

// ---------------------------------------------------------------------------
extern "C" void kernel_launch(void* const* d_in, const int* in_sizes, int n_in,
                              void* d_out, int out_size, void* d_ws, size_t ws_size,
                              hipStream_t stream) {
  const float* x    = (const float*)d_in[0];
  const float* d1_w = (const float*)d_in[2];
  const float* d2_w = (const float*)d_in[3];
  const float* d3_w = (const float*)d_in[4];
  const float* d4_w = (const float*)d_in[5];
  const float* q1_w = (const float*)d_in[6];
  const float* q1_b = (const float*)d_in[7];
  const float* q2_w = (const float*)d_in[8];
  const float* q2_b = (const float*)d_in[9];
  const float* q3_w = (const float*)d_in[10];
  const float* q3_b = (const float*)d_in[11];
  const float* up_w = (const float*)d_in[12];
  const float* up_b = (const float*)d_in[13];
  const float* c1_w = (const float*)d_in[14];
  const float* c1_b = (const float*)d_in[15];
  const float* c1_a = (const float*)d_in[16];
  const float* c2_w = (const float*)d_in[17];
  const float* c2_b = (const float*)d_in[18];
  const float* c2_a = (const float*)d_in[19];
  const float* c3_w = (const float*)d_in[20];
  const float* c3_b = (const float*)d_in[21];
  const float* c3_a = (const float*)d_in[22];
  const float* c4_w = (const float*)d_in[23];
  const float* c4_b = (const float*)d_in[24];
  const float* c4_a = (const float*)d_in[25];
  const float* c5_w = (const float*)d_in[26];
  const float* c5_b = (const float*)d_in[27];

  float* out = (float*)d_out;
  float* ws  = (float*)d_ws;

  const size_t B5  = (size_t)N_B * 256 * IMG * IMG;
  const size_t SML = (size_t)N_B * 154 * 36;
  float* out_b5    = out;
  float* out_xcomp = out + B5;
  float* out_x4    = out + B5 + SML;

  const size_t PADBUF = (size_t)N_B * P * P * 64 / 2;   // floats per padded bf16 buf
  size_t off = 0;
  float* h1   = ws + off; off += (size_t)N_B * 16 * 48 * 48;
  float* h2t  = ws + off; off += (size_t)N_B * 144 * 256;
  float* h3t  = ws + off; off += (size_t)N_B * 36 * 1024;
  float* w3p  = ws + off; off += (size_t)4 * 256 * 1024;
  float* d4t  = ws + off; off += (size_t)1024 * 160;
  float* qt   = ws + off; off += (size_t)3 * 154 * 160;
  float* upt  = ws + off; off += (size_t)154 * 1024;
  float* d2t  = ws + off; off += (size_t)256 * 16 * 16;
  float* ybuf = ws + off; off += (size_t)N_B * IMG * IMG;
  short* sl0  = (short*)(ws + off); off += PADBUF;
  short* sl1  = (short*)(ws + off); off += PADBUF;
  short* sl2  = (short*)(ws + off); off += PADBUF;
  short* sl3  = (short*)(ws + off); off += PADBUF;
  short* wb2  = (short*)(ws + off); off += 9 * 64 * 64 / 2;
  short* wb3  = (short*)(ws + off); off += 9 * 64 * 64 / 2;
  short* wb4  = (short*)(ws + off); off += 9 * 64 * 64 / 2;
  short* wb5  = (short*)(ws + off); off += 9 * 256 * 64 / 2;

  // merged prep (one launch): conv packs + d3 pack + rings + transposes
  k_prep<<<(PREPN + 255) / 256, 256, 0, stream>>>(
      c2_w, c3_w, c4_w, c5_w, d3_w, d4_w, q1_w, q2_w, q3_w, up_w, d2_w,
      wb2, wb3, wb4, wb5, w3p, d4t, qt, upt, d2t, sl0, sl1, sl2, sl3);

  // ---- down path ----
  k_d1<<<(N_B * 16 * 48 * 48 + 255) / 256, 256, 0, stream>>>(x, d1_w, h1);
  k_d2<<<(N_B * 144 * 256 + 255) / 256, 256, 0, stream>>>(h1, d2t, h2t);
  k_d3<<<(N_B * 36 * 1024 + 255) / 256, 256, 0, stream>>>(h2t, w3p, h3t);

  // ---- fused d4 + quantize + qcm x3 + up + depth_to_space ----
  k_mid<<<N_B * 36, 512, 0, stream>>>(h3t, d4t, qt, q1_b, q2_b, q3_b,
                                      upt, up_b, out_x4, out_xcomp, ybuf);

  // ---- refinement CNN ----
  k_c1b<<<(N_B * IMG * IMG + 255) / 256, 256, 0, stream>>>(ybuf, c1_w, c1_b, c1_a,
                                                           sl1 /*B1*/, sl0 /*S1*/);

  dim3 cg(4, 48, N_B);   // 4x48 tile: 768 blocks = 3/CU exact
  // c2: in S1(sl0), bprev B1(sl1) -> B2(sl2), S2(sl3)
  k_conv3x3n<0><<<cg, 256, 0, stream>>>(sl0, sl1, wb2, c2_b, c2_a, sl2, sl3);
  // c3: in S2(sl3), bprev B2(sl2) -> B3(sl1), S3(sl0)
  k_conv3x3n<0><<<cg, 256, 0, stream>>>(sl3, sl2, wb3, c3_b, c3_a, sl1, sl0);
  // c4: in S3(sl0), bprev B3(sl1) -> S4(sl3)
  k_conv3x3n<1><<<cg, 256, 0, stream>>>(sl0, sl1, wb4, c4_b, c4_a, nullptr, sl3);
  // c5: in S4(sl3) -> d_out fp32 NCHW; 4x48 tile
  dim3 cg5(4, 48, N_B * 4);
  k_conv5n<<<cg5, 256, 0, stream>>>(sl3, wb5, c5_b, out_b5);
}